// Round 8
// baseline (1124.330 us; speedup 1.0000x reference)
//
#include <hip/hip_runtime.h>
#include <hip/hip_bf16.h>

// Autoformer encoder, MI355X. Round 8 = round 3 kernel (5 infra failures, never ran).
// - 256x128 block tile, BK=32, 8 waves (4Mx2N), 64x64 per wave, 3-term h/l split.
// - 3-slot LDS ring (3 x 48 KB): stage tile t+2 while computing tile t.
//   Counted s_waitcnt vmcnt(6) at tile top (never 0 in steady state), raw
//   s_barrier + sched_barrier(0) fence, s_setprio(1) around MFMA clusters.
// - Staging/swizzle byte-math identical to round 2 (verified: 0 bank conflicts).
// Numerics unchanged vs round 2 (3-term bf16 split, fp32 accum).

#define LQ 3072
#define DD 512
#define BB 8
#define MTOT (BB * LQ)   // 24576
#define KTOP 8
#define KSZ 25
#define KHALF 12
#define KK 512           // K of every GEMM
#define KB (KK * 2)      // bf16 row bytes = 1024
#define SLOT 49152       // 48 KB ring slot: [Ah 16K][Al 16K][Bh 8K][Bl 8K]
#define NT 16            // K tiles (512 / 32)

typedef unsigned short ushort_t;
typedef __attribute__((ext_vector_type(4))) float f32x4;
typedef __attribute__((ext_vector_type(8))) short s16x8;
typedef __attribute__((ext_vector_type(4))) short s16x4;

typedef __attribute__((address_space(1))) unsigned int u32_g;
typedef __attribute__((address_space(3))) unsigned int u32_l;

__device__ __forceinline__ ushort_t f2bfbits(float x) {
  __hip_bfloat16 h = __float2bfloat16(x);
  return __builtin_bit_cast(unsigned short, h);
}
__device__ __forceinline__ float bfbits2f(ushort_t s) {
  __hip_bfloat16 h = __builtin_bit_cast(__hip_bfloat16, (unsigned short)s);
  return __bfloat162float(h);
}

__device__ __forceinline__ void gload_lds16(const void* g, void* l) {
  __builtin_amdgcn_global_load_lds((const u32_g*)g, (u32_l*)l, 16, 0, 0);
}

#define MFMA3(m, n)                                                                       \
  acc[m][n] = __builtin_amdgcn_mfma_f32_16x16x32_bf16(ah[m], bh[n], acc[m][n], 0, 0, 0); \
  acc[m][n] = __builtin_amdgcn_mfma_f32_16x16x32_bf16(ah[m], bl[n], acc[m][n], 0, 0, 0); \
  acc[m][n] = __builtin_amdgcn_mfma_f32_16x16x32_bf16(al[m], bh[n], acc[m][n], 0, 0, 0);

// ---------------------------------------------------------------------------
// Core: wave (wm,wn) computes 64x64 of the 256x128 block; acc[4][4] of 16x16.
// A tile 256x32 (h+l), B tile 128x32 (h+l) per K-step, pair-packed 128B lines,
// slot XOR swizzle (round-2 scheme, proven conflict-free).
// ---------------------------------------------------------------------------
__device__ __forceinline__ void core256(
    const ushort_t* __restrict__ Ahp, const ushort_t* __restrict__ Alp,
    const ushort_t* __restrict__ Bhp, const ushort_t* __restrict__ Blp,
    int arow0, int brow0, char* lds, f32x4 acc[4][4]) {
  const int tid = threadIdx.x, lane = tid & 63, w = tid >> 6;
  const int wm = w >> 1, wn = w & 1;
  const int c = lane & 15, qd = lane >> 4;
  const int L0 = lane >> 3, sl = lane & 7, u = sl ^ L0;

  // 6 staging descriptors per wave: 48 chunks of 1 KB over {Ah16,Al16,Bh8,Bl8}
  const char* gp[6];
  int lo[6];
#pragma unroll
  for (int i = 0; i < 6; i++) {
    int g = 6 * w + i;
    const ushort_t* src;
    int tbase, cin, rbase;
    if (g < 16)      { src = Ahp; tbase = 0;     cin = g;      rbase = arow0; }
    else if (g < 32) { src = Alp; tbase = 16384; cin = g - 16; rbase = arow0; }
    else if (g < 40) { src = Bhp; tbase = 32768; cin = g - 32; rbase = brow0; }
    else             { src = Blp; tbase = 40960; cin = g - 40; rbase = brow0; }
    gp[i] = (const char*)src + (size_t)(rbase + 16 * cin + 2 * L0 + (u >> 2)) * KB +
            (u & 3) * 16;
    lo[i] = tbase + cin * 1024;
  }

  // fragment read offsets (slot-relative)
  int aoh[4], boh[4];
#pragma unroll
  for (int m = 0; m < 4; m++) {
    int r = wm * 64 + m * 16 + c, L = r >> 1;
    aoh[m] = L * 128 + (((((r & 1) << 2) | qd) ^ (L & 7)) << 4);
    int rb = wn * 64 + m * 16 + c, Lb = rb >> 1;
    boh[m] = 32768 + Lb * 128 + (((((rb & 1) << 2) | qd) ^ (Lb & 7)) << 4);
  }

#pragma unroll
  for (int m = 0; m < 4; m++)
#pragma unroll
    for (int n = 0; n < 4; n++) acc[m][n] = 0.f;

  // prologue: stage tiles 0 and 1 (6+6 loads per wave, in order)
#pragma unroll
  for (int i = 0; i < 6; i++) gload_lds16(gp[i], lds + lo[i]);
#pragma unroll
  for (int i = 0; i < 6; i++) gload_lds16(gp[i] + 64, lds + SLOT + lo[i]);

  int sb = 0, sb2 = 2 * SLOT;
  for (int t = 0; t < NT; t++) {
    // tile-top: own slot-t loads are the oldest 6; keep t+1's 6 in flight
    if (t < NT - 1) asm volatile("s_waitcnt vmcnt(6)" ::: "memory");
    else            asm volatile("s_waitcnt vmcnt(0)" ::: "memory");
    __builtin_amdgcn_s_barrier();
    __builtin_amdgcn_sched_barrier(0);

    const char* lb = lds + sb;
    s16x8 ah[4], al[4], bh[4], bl[4];
    // ---- phase 0: issue 3 loads for t+2, read A frags + B n0/n1, MFMA 24 ----
    if (t + 2 < NT) {
      const int go = (t + 2) * 64;
#pragma unroll
      for (int i = 0; i < 3; i++) gload_lds16(gp[i] + go, lds + sb2 + lo[i]);
    }
#pragma unroll
    for (int m = 0; m < 4; m++) {
      ah[m] = *(const s16x8*)(lb + aoh[m]);
      al[m] = *(const s16x8*)(lb + aoh[m] + 16384);
    }
#pragma unroll
    for (int n = 0; n < 2; n++) {
      bh[n] = *(const s16x8*)(lb + boh[n]);
      bl[n] = *(const s16x8*)(lb + boh[n] + 8192);
    }
    __builtin_amdgcn_s_barrier();
    __builtin_amdgcn_s_setprio(1);
#pragma unroll
    for (int n = 0; n < 2; n++) {
#pragma unroll
      for (int m = 0; m < 4; m++) { MFMA3(m, n) }
    }
    __builtin_amdgcn_s_setprio(0);
    __builtin_amdgcn_s_barrier();
    // ---- phase 1: issue 3 loads for t+2, read B n2/n3, MFMA 24 ----
    if (t + 2 < NT) {
      const int go = (t + 2) * 64;
#pragma unroll
      for (int i = 3; i < 6; i++) gload_lds16(gp[i] + go, lds + sb2 + lo[i]);
    }
#pragma unroll
    for (int n = 2; n < 4; n++) {
      bh[n] = *(const s16x8*)(lb + boh[n]);
      bl[n] = *(const s16x8*)(lb + boh[n] + 8192);
    }
    __builtin_amdgcn_s_barrier();
    __builtin_amdgcn_s_setprio(1);
#pragma unroll
    for (int n = 2; n < 4; n++) {
#pragma unroll
      for (int m = 0; m < 4; m++) { MFMA3(m, n) }
    }
    __builtin_amdgcn_s_setprio(0);

    sb += SLOT;  if (sb == 3 * SLOT)  sb = 0;
    sb2 += SLOT; if (sb2 == 3 * SLOT) sb2 = 0;
  }
}

// C = A*B^T variants. OUTMODE: 0 = fp32, 1 = bf16 h/l. RESMODE: 0 none, 1 = h/l residual.
template <int OUTMODE, int RESMODE, int RELU>
__global__ __launch_bounds__(512, 2) void gemm_bf16x3(
    const ushort_t* __restrict__ Ah, const ushort_t* __restrict__ Al,
    const ushort_t* __restrict__ Bh, const ushort_t* __restrict__ Bl,
    const float* __restrict__ bias,
    const ushort_t* __restrict__ resH, const ushort_t* __restrict__ resL,
    float* __restrict__ outF, ushort_t* __restrict__ outH, ushort_t* __restrict__ outL) {
  __shared__ alignas(16) char lds[3 * SLOT];
  const int m0 = blockIdx.y * 256, n0 = blockIdx.x * 128;
  f32x4 acc[4][4];
  core256(Ah, Al, Bh, Bl, m0, n0, lds, acc);

  const int tid = threadIdx.x, lane = tid & 63, w = tid >> 6;
  const int wm = w >> 1, wn = w & 1, qd = lane >> 4, c = lane & 15;
#pragma unroll
  for (int m = 0; m < 4; m++)
#pragma unroll
    for (int n = 0; n < 4; n++) {
      int col = n0 + wn * 64 + n * 16 + c;
      float badd = bias ? bias[col] : 0.f;
#pragma unroll
      for (int r = 0; r < 4; r++) {
        int row = m0 + wm * 64 + m * 16 + 4 * qd + r;
        size_t off = (size_t)row * DD + col;
        float val = acc[m][n][r] + badd;
        if (RESMODE == 1) val += bfbits2f(resH[off]) + bfbits2f(resL[off]);
        if (RELU) val = fmaxf(val, 0.f);
        if (OUTMODE == 0) {
          outF[off] = val;
        } else {
          ushort_t h = f2bfbits(val);
          outH[off] = h;
          outL[off] = f2bfbits(val - bfbits2f(h));
        }
      }
    }
}

// Batched Q*K^T, wrapped-diagonal-sum epilogue -> mean_corr raw sums.
__global__ __launch_bounds__(512, 2) void corr_gemm(
    const ushort_t* __restrict__ Qh, const ushort_t* __restrict__ Ql,
    const ushort_t* __restrict__ Kh, const ushort_t* __restrict__ Kl,
    float* __restrict__ mc) {
  __shared__ alignas(16) char lds[3 * SLOT];
  __shared__ float bins[383];
  const int b = blockIdx.z;
  const int m0 = blockIdx.y * 256, n0 = blockIdx.x * 128;
  if (threadIdx.x < 383) bins[threadIdx.x] = 0.f;  // ordered by core's first barrier
  f32x4 acc[4][4];
  core256(Qh, Ql, Kh, Kl, b * LQ + m0, b * LQ + n0, lds, acc);

  const int tid = threadIdx.x, lane = tid & 63, w = tid >> 6;
  const int wm = w >> 1, wn = w & 1, qd = lane >> 4, c = lane & 15;

  float psum[7][4];
#pragma unroll
  for (int d = 0; d < 7; d++)
#pragma unroll
    for (int r = 0; r < 4; r++) psum[d][r] = 0.f;
#pragma unroll
  for (int m = 0; m < 4; m++)
#pragma unroll
    for (int n = 0; n < 4; n++) {
      int d = m - n + 3;
#pragma unroll
      for (int r = 0; r < 4; r++) psum[d][r] += acc[m][n][r];
    }

  const int lanebase = 64 * wm - 64 * wn + 4 * qd - c + 127;  // +16(d-3)+r in [0,382]
#pragma unroll
  for (int d = 0; d < 7; d++)
#pragma unroll
    for (int r = 0; r < 4; r++) atomicAdd(&bins[lanebase + 16 * (d - 3) + r], psum[d][r]);
  __syncthreads();

  if (tid < 383) {
    int tau = 256 * (int)blockIdx.y - 128 * (int)blockIdx.x + tid - 127;
    tau = ((tau % LQ) + LQ) % LQ;
    atomicAdd(&mc[b * LQ + tau], bins[tid]);
  }
}

// ---------------------------------------------------------------------------
// Small kernels (unchanged from round 2)
// ---------------------------------------------------------------------------
struct P8 {
  const float* p[8];
};

__global__ void transpose_split(P8 srcs, ushort_t* __restrict__ dH, ushort_t* __restrict__ dL) {
  __shared__ float t[32][33];
  const int i = blockIdx.z;
  const float* src = srcs.p[i];
  const size_t base = (size_t)i * DD * DD;
  const int x0 = blockIdx.x * 32, y0 = blockIdx.y * 32;
  const int tx = threadIdx.x, ty = threadIdx.y;  // (32,8)
#pragma unroll
  for (int j = 0; j < 4; j++) t[ty + 8 * j][tx] = src[(size_t)(y0 + ty + 8 * j) * DD + x0 + tx];
  __syncthreads();
#pragma unroll
  for (int j = 0; j < 4; j++) {
    float v = t[tx][ty + 8 * j];
    size_t o = base + (size_t)(x0 + ty + 8 * j) * DD + (y0 + tx);
    ushort_t h = f2bfbits(v);
    dH[o] = h;
    dL[o] = f2bfbits(v - bfbits2f(h));
  }
}

__global__ void split_f32(const float* __restrict__ x, ushort_t* __restrict__ h,
                          ushort_t* __restrict__ l, int n4) {
  int i = blockIdx.x * blockDim.x + threadIdx.x;
  if (i >= n4) return;
  f32x4 v = *reinterpret_cast<const f32x4*>(x + (size_t)i * 4);
  s16x4 hv, lv;
#pragma unroll
  for (int j = 0; j < 4; j++) {
    ushort_t hb = f2bfbits(v[j]);
    hv[j] = (short)hb;
    lv[j] = (short)f2bfbits(v[j] - bfbits2f(hb));
  }
  *reinterpret_cast<s16x4*>(h + (size_t)i * 4) = hv;
  *reinterpret_cast<s16x4*>(l + (size_t)i * 4) = lv;
}

__global__ void zero_f32(float* __restrict__ p, int n) {
  int i = blockIdx.x * blockDim.x + threadIdx.x;
  if (i < n) p[i] = 0.f;
}

__global__ void topk_softmax(const float* __restrict__ mc, int* __restrict__ delays,
                             float* __restrict__ weights) {
  const int b = blockIdx.x, tid = threadIdx.x;
  __shared__ float vals[LQ];
  __shared__ float rv[256];
  __shared__ int ri[256];
  __shared__ float topv[KTOP];
  __shared__ int topi[KTOP];
  for (int i = tid; i < LQ; i += 256) vals[i] = mc[b * LQ + i] * (1.0f / 512.0f);
  __syncthreads();
  for (int t = 0; t < KTOP; t++) {
    float bv = -1e30f;
    int bi = 0x7fffffff;
    for (int i = tid; i < LQ; i += 256) {
      float v = vals[i];
      if (v > bv || (v == bv && i < bi)) { bv = v; bi = i; }
    }
    rv[tid] = bv;
    ri[tid] = bi;
    __syncthreads();
    for (int s = 128; s > 0; s >>= 1) {
      if (tid < s) {
        if (rv[tid + s] > rv[tid] || (rv[tid + s] == rv[tid] && ri[tid + s] < ri[tid])) {
          rv[tid] = rv[tid + s];
          ri[tid] = ri[tid + s];
        }
      }
      __syncthreads();
    }
    if (tid == 0) {
      topv[t] = rv[0];
      topi[t] = ri[0];
      vals[ri[0]] = -1e38f;
    }
    __syncthreads();
  }
  if (tid == 0) {
    float mx = topv[0];
#pragma unroll
    for (int i = 1; i < KTOP; i++) mx = fmaxf(mx, topv[i]);
    float e[KTOP], s = 0.f;
#pragma unroll
    for (int i = 0; i < KTOP; i++) {
      e[i] = expf(topv[i] - mx);
      s += e[i];
    }
#pragma unroll
    for (int i = 0; i < KTOP; i++) {
      weights[b * KTOP + i] = e[i] / s;
      delays[b * KTOP + i] = topi[i];
    }
  }
}

// attn[b,l,:] = sum_i w[b,i] * v[b,(l+delay_i)%L,:]  -> bf16 h/l output
__global__ void attn_gather(const float* __restrict__ v, const int* __restrict__ delays,
                            const float* __restrict__ w, ushort_t* __restrict__ oH,
                            ushort_t* __restrict__ oL) {
  int idx = blockIdx.x * blockDim.x + threadIdx.x;
  const int total = BB * LQ * (DD / 4);
  if (idx >= total) return;
  int b = idx / (LQ * (DD / 4));
  int rem = idx % (LQ * (DD / 4));
  int l = rem / (DD / 4), dq = rem % (DD / 4);
  f32x4 acc = 0.f;
#pragma unroll
  for (int i = 0; i < KTOP; i++) {
    int d = delays[b * KTOP + i];
    float wi = w[b * KTOP + i];
    int ls = (l + d) % LQ;
    f32x4 vv = *reinterpret_cast<const f32x4*>(v + ((size_t)b * LQ + ls) * DD + dq * 4);
    acc += vv * wi;
  }
  size_t o = ((size_t)b * LQ + l) * DD + dq * 4;
  s16x4 hv, lv;
#pragma unroll
  for (int j = 0; j < 4; j++) {
    ushort_t hb = f2bfbits(acc[j]);
    hv[j] = (short)hb;
    lv[j] = (short)f2bfbits(acc[j] - bfbits2f(hb));
  }
  *reinterpret_cast<s16x4*>(oH + o) = hv;
  *reinterpret_cast<s16x4*>(oL + o) = lv;
}

// seasonal = x - movavg_25(x), TF-SAME counts. OUT_HL: 1 -> bf16 h/l, 0 -> fp32.
template <int OUT_HL>
__global__ void decomp_kernel(const float* __restrict__ x, float* __restrict__ outF,
                              ushort_t* __restrict__ outH, ushort_t* __restrict__ outL) {
  __shared__ float tile[64 + 2 * KHALF][64];
  const int l0 = blockIdx.x * 64, d0 = blockIdx.y * 64, b = blockIdx.z;
  const int tx = threadIdx.x & 63, ty = threadIdx.x >> 6;
  const float* xb = x + (size_t)b * LQ * DD;
  for (int r = ty; r < 64 + 2 * KHALF; r += 4) {
    int l = l0 + r - KHALF;
    tile[r][tx] = (l >= 0 && l < LQ) ? xb[(size_t)l * DD + d0 + tx] : 0.f;
  }
  __syncthreads();
#pragma unroll
  for (int j = 0; j < 16; j++) {
    int lr = ty + 4 * j;
    int l = l0 + lr;
    float s = 0.f;
#pragma unroll
    for (int t = 0; t < KSZ; t++) s += tile[lr + t][tx];
    int lo = max(0, l - KHALF), hi = min(LQ - 1, l + KHALF);
    float val = tile[lr + KHALF][tx] - s / (float)(hi - lo + 1);
    size_t o = ((size_t)b * LQ + l) * DD + d0 + tx;
    if (OUT_HL) {
      ushort_t h = f2bfbits(val);
      outH[o] = h;
      outL[o] = f2bfbits(val - bfbits2f(h));
    } else {
      outF[o] = val;
    }
  }
}

// ---------------------------------------------------------------------------
extern "C" void kernel_launch(void* const* d_in, const int* in_sizes, int n_in,
                              void* d_out, int out_size, void* d_ws, size_t ws_size,
                              hipStream_t stream) {
  const float* inputs = (const float*)d_in[0];
  const float* b_res = (const float*)d_in[2];
  const float* b_in = (const float*)d_in[4];
  const float* bq = (const float*)d_in[6];
  const float* bk = (const float*)d_in[8];
  const float* bv = (const float*)d_in[10];
  const float* bo = (const float*)d_in[12];
  float* outp = (float*)d_out;

  // workspace: [0,4M) WTh, [4M,8M) WTl, [8M,+) mc/delays/weights, [16M..208M) R0..R3
  char* ws = (char*)d_ws;
  ushort_t* WTh = (ushort_t*)ws;
  ushort_t* WTl = (ushort_t*)(ws + (4u << 20));
  float* mean_corr = (float*)(ws + (8u << 20));
  int* delays = (int*)(ws + (8u << 20) + 98304);
  float* weights = (float*)(ws + (8u << 20) + 98304 + 256);
  char* R0 = ws + (16u << 20);
  char* R1 = ws + (64u << 20);
  char* R2 = ws + (112u << 20);
  char* R3 = ws + (160u << 20);
  const size_t HALF = 24u << 20;  // h at R, l at R+24MB
  ushort_t *R0h = (ushort_t*)R0, *R0l = (ushort_t*)(R0 + HALF);
  ushort_t *R1h = (ushort_t*)R1, *R1l = (ushort_t*)(R1 + HALF);
  ushort_t *R2h = (ushort_t*)R2, *R2l = (ushort_t*)(R2 + HALF);
  ushort_t *R3h = (ushort_t*)R3, *R3l = (ushort_t*)(R3 + HALF);
  const size_t WS1 = (size_t)DD * DD;

  P8 wp;
  wp.p[0] = (const float*)d_in[1];   // W_res
  wp.p[1] = (const float*)d_in[3];   // W_in
  wp.p[2] = (const float*)d_in[5];   // Wq
  wp.p[3] = (const float*)d_in[7];   // Wk
  wp.p[4] = (const float*)d_in[9];   // Wv
  wp.p[5] = (const float*)d_in[11];  // Wo
  wp.p[6] = (const float*)d_in[13];  // Wc1
  wp.p[7] = (const float*)d_in[14];  // Wc2

  transpose_split<<<dim3(16, 16, 8), dim3(32, 8), 0, stream>>>(wp, WTh, WTl);
  split_f32<<<(MTOT * DD / 4 + 255) / 256, 256, 0, stream>>>(inputs, R1h, R1l, MTOT * DD / 4);

  const dim3 G(DD / 128, MTOT / 256);  // (4, 96), 512 threads
  // proj = in @ W_res + b_res  -> R0 h/l
  gemm_bf16x3<1, 0, 0><<<G, 512, 0, stream>>>(R1h, R1l, WTh + 0 * WS1, WTl + 0 * WS1, b_res,
                                              nullptr, nullptr, nullptr, R0h, R0l);
  // x1 = proj @ W_in + b_in  -> R1 h/l
  gemm_bf16x3<1, 0, 0><<<G, 512, 0, stream>>>(R0h, R0l, WTh + 1 * WS1, WTl + 1 * WS1, b_in,
                                              nullptr, nullptr, nullptr, R1h, R1l);
  // q -> R2 h/l ; k -> R3 h/l
  gemm_bf16x3<1, 0, 0><<<G, 512, 0, stream>>>(R1h, R1l, WTh + 2 * WS1, WTl + 2 * WS1, bq,
                                              nullptr, nullptr, nullptr, R2h, R2l);
  gemm_bf16x3<1, 0, 0><<<G, 512, 0, stream>>>(R1h, R1l, WTh + 3 * WS1, WTl + 3 * WS1, bk,
                                              nullptr, nullptr, nullptr, R3h, R3l);
  // mean_corr
  zero_f32<<<(BB * LQ + 255) / 256, 256, 0, stream>>>(mean_corr, BB * LQ);
  corr_gemm<<<dim3(LQ / 128, LQ / 256, BB), 512, 0, stream>>>(R2h, R2l, R3h, R3l, mean_corr);
  topk_softmax<<<BB, 256, 0, stream>>>(mean_corr, delays, weights);
  // v -> R2 fp32 (q dead)
  gemm_bf16x3<0, 0, 0><<<G, 512, 0, stream>>>(R1h, R1l, WTh + 4 * WS1, WTl + 4 * WS1, bv,
                                              nullptr, nullptr, (float*)R2, nullptr, nullptr);
  // attn -> R3 h/l (k dead)
  attn_gather<<<(BB * LQ * (DD / 4) + 255) / 256, 256, 0, stream>>>((const float*)R2, delays,
                                                                    weights, R3h, R3l);
  // x2 = attn @ Wo + bo + proj -> R1 fp32 (x1 dead)
  gemm_bf16x3<0, 1, 0><<<G, 512, 0, stream>>>(R3h, R3l, WTh + 5 * WS1, WTl + 5 * WS1, bo,
                                              R0h, R0l, (float*)R1, nullptr, nullptr);
  // seasonal -> R0 h/l (proj dead)
  decomp_kernel<1><<<dim3(LQ / 64, DD / 64, BB), 256, 0, stream>>>((const float*)R1, nullptr,
                                                                   R0h, R0l);
  // y1 = relu(seasonal @ Wc1) -> R2 h/l (v dead)
  gemm_bf16x3<1, 0, 1><<<G, 512, 0, stream>>>(R0h, R0l, WTh + 6 * WS1, WTl + 6 * WS1, nullptr,
                                              nullptr, nullptr, nullptr, R2h, R2l);
  // y2 = y1 @ Wc2 -> R1 fp32 (x2 dead)
  gemm_bf16x3<0, 0, 0><<<G, 512, 0, stream>>>(R2h, R2l, WTh + 7 * WS1, WTl + 7 * WS1, nullptr,
                                              nullptr, nullptr, (float*)R1, nullptr, nullptr);
  // out = decomp(y2)
  decomp_kernel<0><<<dim3(LQ / 64, DD / 64, BB), 256, 0, stream>>>((const float*)R1, outp,
                                                                   nullptr, nullptr);
}